// Round 1
// baseline (87.482 us; speedup 1.0000x reference)
//
#include <hip/hip_runtime.h>
#include <math.h>

// Problem constants (reference: B=4, N=2048, H=5, L=3)
#define B_ 4
#define N_ 2048
#define H_ 5
#define L_ 3
#define EPS_ 1e-6f

constexpr int RPW = 2;            // rows per wave
constexpr int WAVES = 4;          // waves per block (256 threads)
constexpr int RPB = RPW * WAVES;  // rows per block = 8
constexpr float LOG2E = 1.4426950408889634f;

// Attention for one layer:
//   a[b,i] = sum_h w0[h] * (Num_i - e_ii*v_i) / D_i
//   D_i   = sum_j exp(q_i * k_j),  Num_i = sum_j exp(q_i*k_j)*v_j
// where q_i = cur[b,i]*WQ[h,i], k_j = cur[b,j]*WK[h,j], v_j = cur[b,j]*WV[h,j].
__global__ __launch_bounds__(256) void attn_kernel(
    const float* __restrict__ cur,   // [B,N] current residual stream
    const float* __restrict__ WQ,    // [H,N] (layer slice)
    const float* __restrict__ WK,    // [H,N]
    const float* __restrict__ WV,    // [H,N]
    const float* __restrict__ W0,    // [H]
    float* __restrict__ a)           // [B,N] output
{
  __shared__ float2 kv[N_];  // (k_j * log2e, v_j) for current head: 16 KB

  const int bid = blockIdx.x;
  const int b = bid / (N_ / RPB);
  const int i0 = (bid % (N_ / RPB)) * RPB;
  const int tid = threadIdx.x;
  const int wave = tid >> 6;
  const int lane = tid & 63;
  const float* curb = cur + b * N_;

  float acc[RPW];
#pragma unroll
  for (int r = 0; r < RPW; ++r) acc[r] = 0.f;

  for (int h = 0; h < H_; ++h) {
    __syncthreads();  // protect LDS reuse from previous head
    for (int j = tid; j < N_; j += 256) {
      float oj = curb[j];
      kv[j] = make_float2(oj * WK[h * N_ + j] * LOG2E, oj * WV[h * N_ + j]);
    }
    __syncthreads();
    const float w0h = W0[h];
#pragma unroll
    for (int r = 0; r < RPW; ++r) {
      const int i = i0 + wave * RPW + r;
      const float s = curb[i] * WQ[h * N_ + i];  // q_i (log2e folded into k')
      float d = 0.f, n = 0.f;
#pragma unroll 8
      for (int it = 0; it < N_ / 64; ++it) {
        float2 kvj = kv[it * 64 + lane];
        float e = __builtin_amdgcn_exp2f(s * kvj.x);
        d += e;
        n = fmaf(e, kvj.y, n);
      }
      // 64-lane butterfly reduction; all lanes end with the full sums
#pragma unroll
      for (int off = 32; off; off >>= 1) {
        d += __shfl_xor(d, off);
        n += __shfl_xor(n, off);
      }
      float2 kvi = kv[i];
      float ed = __builtin_amdgcn_exp2f(s * kvi.x);  // diagonal term
      acc[r] = fmaf(w0h, (n - ed * kvi.y) / d, acc[r]);
    }
  }
  if (lane == 0) {
#pragma unroll
    for (int r = 0; r < RPW; ++r)
      a[b * N_ + i0 + wave * RPW + r] = acc[r];
  }
}

// out[b,:] += gamma*(a-mean)/(sqrt(var_unbiased)+eps) + beta   (one block per b)
__global__ __launch_bounds__(256) void ln_kernel(
    const float* __restrict__ a, const float* __restrict__ gamma,
    const float* __restrict__ beta, float* __restrict__ out)
{
  const int b = blockIdx.x;
  const int tid = threadIdx.x;
  const float* ab = a + b * N_;
  constexpr int PT = N_ / 256;  // 8 elements per thread

  float vals[PT];
  float sum = 0.f;
#pragma unroll
  for (int r = 0; r < PT; ++r) {
    vals[r] = ab[tid + r * 256];
    sum += vals[r];
  }

  __shared__ float red[WAVES];
  __shared__ float red2[WAVES];
#pragma unroll
  for (int off = 32; off; off >>= 1) sum += __shfl_xor(sum, off);
  if ((tid & 63) == 0) red[tid >> 6] = sum;
  __syncthreads();
  const float mean = (red[0] + red[1] + red[2] + red[3]) * (1.f / N_);

  float vs = 0.f;
#pragma unroll
  for (int r = 0; r < PT; ++r) {
    float t = vals[r] - mean;
    vs = fmaf(t, t, vs);
  }
#pragma unroll
  for (int off = 32; off; off >>= 1) vs += __shfl_xor(vs, off);
  if ((tid & 63) == 0) red2[tid >> 6] = vs;
  __syncthreads();
  const float var = (red2[0] + red2[1] + red2[2] + red2[3]) * (1.f / (N_ - 1));
  const float inv = 1.f / (sqrtf(var) + EPS_);

#pragma unroll
  for (int r = 0; r < PT; ++r) {
    int i = tid + r * 256;
    out[b * N_ + i] += gamma[i] * (vals[r] - mean) * inv + beta[i];
  }
}

extern "C" void kernel_launch(void* const* d_in, const int* in_sizes, int n_in,
                              void* d_out, int out_size, void* d_ws, size_t ws_size,
                              hipStream_t stream) {
  const float* x     = (const float*)d_in[0];
  const float* WQ    = (const float*)d_in[1];  // [L,H,N]
  const float* WK    = (const float*)d_in[2];
  const float* WV    = (const float*)d_in[3];
  const float* W0    = (const float*)d_in[4];  // [L,H]
  const float* gamma = (const float*)d_in[5];
  const float* beta  = (const float*)d_in[6];
  float* out = (float*)d_out;                  // running residual stream [B,N]
  float* a   = (float*)d_ws;                   // attention output scratch [B,N]

  // out = x
  hipMemcpyAsync(out, x, B_ * N_ * sizeof(float), hipMemcpyDeviceToDevice, stream);

  for (int l = 0; l < L_; ++l) {
    attn_kernel<<<B_ * (N_ / RPB), 256, 0, stream>>>(
        out, WQ + l * H_ * N_, WK + l * H_ * N_, WV + l * H_ * N_, W0 + l * H_, a);
    ln_kernel<<<B_, 256, 0, stream>>>(a, gamma, beta, out);
  }
}

// Round 2
// 78.279 us; speedup vs baseline: 1.1176x; 1.1176x over previous
//
#include <hip/hip_runtime.h>
#include <math.h>

// Problem constants (reference: B=4, N=2048, H=5, L=3)
#define B_ 4
#define N_ 2048
#define H_ 5
#define L_ 3
#define EPS_ 1e-6f

constexpr int RPW = 4;            // rows per wave (register-tiled)
constexpr int WAVES = 4;          // waves per block (256 threads)
constexpr int RPB = RPW * WAVES;  // rows per block = 16
constexpr int ITERS = N_ / 64;    // 32 j-chunks per lane
constexpr float LOG2E = 1.4426950408889634f;

// Attention for one layer:
//   a[b,i] = sum_h w0[h] * (Num_i - e_ii*v_i) / D_i
//   D_i   = sum_j exp(q_i * k_j),  Num_i = sum_j exp(q_i*k_j)*v_j
// where q_i = cur[b,i]*WQ[h,i], k_j = cur[b,j]*WK[h,j], v_j = cur[b,j]*WV[h,j].
// Each wave caches its 32 (k',v) pairs per lane in REGISTERS and reuses them
// across RPW rows -> inner loop is pure VALU/trans, no LDS traffic.
__global__ __launch_bounds__(256) void attn_kernel(
    const float* __restrict__ cur,   // [B,N] current residual stream
    const float* __restrict__ WQ,    // [H,N] (layer slice)
    const float* __restrict__ WK,    // [H,N]
    const float* __restrict__ WV,    // [H,N]
    const float* __restrict__ W0,    // [H]
    float* __restrict__ a)           // [B,N] output
{
  __shared__ float2 kv[N_];  // (k_j * log2e, v_j) for current head: 16 KB

  const int bid = blockIdx.x;
  const int b = bid / (N_ / RPB);
  const int i0 = (bid % (N_ / RPB)) * RPB;
  const int tid = threadIdx.x;
  const int wave = tid >> 6;
  const int lane = tid & 63;
  const float* curb = cur + b * N_;

  float acc[RPW];
#pragma unroll
  for (int r = 0; r < RPW; ++r) acc[r] = 0.f;

  for (int h = 0; h < H_; ++h) {
    __syncthreads();  // protect LDS reuse from previous head
    for (int j = tid; j < N_; j += 256) {
      float oj = curb[j];
      kv[j] = make_float2(oj * WK[h * N_ + j] * LOG2E, oj * WV[h * N_ + j]);
    }
    __syncthreads();

    // Register-cache this lane's 32 (k',v) pairs (fully unrolled -> VGPRs)
    float kx[ITERS], ky[ITERS];
#pragma unroll
    for (int it = 0; it < ITERS; ++it) {
      float2 t = kv[it * 64 + lane];
      kx[it] = t.x;
      ky[it] = t.y;
    }

    float s[RPW], d[RPW], n[RPW];
#pragma unroll
    for (int r = 0; r < RPW; ++r) {
      const int i = i0 + wave * RPW + r;
      s[r] = curb[i] * WQ[h * N_ + i];
      d[r] = 0.f;
      n[r] = 0.f;
    }

#pragma unroll
    for (int it = 0; it < ITERS; ++it) {
#pragma unroll
      for (int r = 0; r < RPW; ++r) {
        float e = __builtin_amdgcn_exp2f(s[r] * kx[it]);
        d[r] += e;
        n[r] = fmaf(e, ky[it], n[r]);
      }
    }

    const float w0h = W0[h];
#pragma unroll
    for (int r = 0; r < RPW; ++r) {
      float dd = d[r], nn = n[r];
#pragma unroll
      for (int off = 32; off; off >>= 1) {
        dd += __shfl_xor(dd, off);
        nn += __shfl_xor(nn, off);
      }
      const int i = i0 + wave * RPW + r;
      float2 kvi = kv[i];
      float ed = __builtin_amdgcn_exp2f(s[r] * kvi.x);  // diagonal term
      acc[r] = fmaf(w0h, (nn - ed * kvi.y) / dd, acc[r]);
    }
  }

  if (lane == 0) {
#pragma unroll
    for (int r = 0; r < RPW; ++r)
      a[b * N_ + i0 + wave * RPW + r] = acc[r];
  }
}

// out[b,:] += gamma*(a-mean)/(sqrt(var_unbiased)+eps) + beta   (one block per b)
__global__ __launch_bounds__(256) void ln_kernel(
    const float* __restrict__ a, const float* __restrict__ gamma,
    const float* __restrict__ beta, float* __restrict__ out)
{
  const int b = blockIdx.x;
  const int tid = threadIdx.x;
  const float* ab = a + b * N_;
  constexpr int PT = N_ / 256;  // 8 elements per thread

  float vals[PT];
  float sum = 0.f;
#pragma unroll
  for (int r = 0; r < PT; ++r) {
    vals[r] = ab[tid + r * 256];
    sum += vals[r];
  }

  __shared__ float red[4];
  __shared__ float red2[4];
#pragma unroll
  for (int off = 32; off; off >>= 1) sum += __shfl_xor(sum, off);
  if ((tid & 63) == 0) red[tid >> 6] = sum;
  __syncthreads();
  const float mean = (red[0] + red[1] + red[2] + red[3]) * (1.f / N_);

  float vs = 0.f;
#pragma unroll
  for (int r = 0; r < PT; ++r) {
    float t = vals[r] - mean;
    vs = fmaf(t, t, vs);
  }
#pragma unroll
  for (int off = 32; off; off >>= 1) vs += __shfl_xor(vs, off);
  if ((tid & 63) == 0) red2[tid >> 6] = vs;
  __syncthreads();
  const float var = (red2[0] + red2[1] + red2[2] + red2[3]) * (1.f / (N_ - 1));
  const float inv = 1.f / (sqrtf(var) + EPS_);

#pragma unroll
  for (int r = 0; r < PT; ++r) {
    int i = tid + r * 256;
    out[b * N_ + i] += gamma[i] * (vals[r] - mean) * inv + beta[i];
  }
}

extern "C" void kernel_launch(void* const* d_in, const int* in_sizes, int n_in,
                              void* d_out, int out_size, void* d_ws, size_t ws_size,
                              hipStream_t stream) {
  const float* x     = (const float*)d_in[0];
  const float* WQ    = (const float*)d_in[1];  // [L,H,N]
  const float* WK    = (const float*)d_in[2];
  const float* WV    = (const float*)d_in[3];
  const float* W0    = (const float*)d_in[4];  // [L,H]
  const float* gamma = (const float*)d_in[5];
  const float* beta  = (const float*)d_in[6];
  float* out = (float*)d_out;                  // running residual stream [B,N]
  float* a   = (float*)d_ws;                   // attention output scratch [B,N]

  // out = x
  hipMemcpyAsync(out, x, B_ * N_ * sizeof(float), hipMemcpyDeviceToDevice, stream);

  for (int l = 0; l < L_; ++l) {
    attn_kernel<<<B_ * (N_ / RPB), 256, 0, stream>>>(
        out, WQ + l * H_ * N_, WK + l * H_ * N_, WV + l * H_ * N_, W0 + l * H_, a);
    ln_kernel<<<B_, 256, 0, stream>>>(a, gamma, beta, out);
  }
}